// Round 1
// baseline (7351.234 us; speedup 1.0000x reference)
//
#include <hip/hip_runtime.h>
#include <hip/hip_bf16.h>
#include <math.h>

typedef __attribute__((ext_vector_type(8))) short short8;
typedef __attribute__((ext_vector_type(4))) float f32x4;

#define M_SZ 32768   // B*T
#define K_SZ 1024
#define N_SZ 1024

__device__ __forceinline__ unsigned short f2bf(float f) {
  union { float f; unsigned u; } v; v.f = f;
  unsigned r = v.u + 0x7fffu + ((v.u >> 16) & 1u);
  return (unsigned short)(r >> 16);
}
__device__ __forceinline__ float bf2f(unsigned short b) {
  union { unsigned u; float f; } v; v.u = ((unsigned)b) << 16;
  return v.f;
}

// Coherent 16B load: bypasses (possibly stale) L1/L2, reads the MALL — the
// cross-XCD coherence point — with NO cache invalidation (the round-1 killer
// was buffer_inv/buffer_wbl2 from acquire/release fences every step).
template <int OFF>
__device__ __forceinline__ short8 ldg_sc1(const unsigned short* p) {
  short8 r;
  asm volatile("global_load_dwordx4 %0, %1, off offset:%c2 sc1"
               : "=v"(r) : "v"(p), "i"(OFF) : "memory");
  return r;
}

// ---------------------------------------------------------------- prep ----
__global__ void prep(const float* __restrict__ seq, const float* __restrict__ Wi,
                     const float* __restrict__ Wh, const float* __restrict__ Wo,
                     unsigned short* __restrict__ seq_bf, unsigned short* __restrict__ Wi_bf,
                     unsigned short* __restrict__ Wh_hi, unsigned short* __restrict__ Wh_lo,
                     unsigned short* __restrict__ Wo_bf, unsigned short* __restrict__ hbuf,
                     unsigned* __restrict__ ctrs) {
  const int stride = gridDim.x * blockDim.x;
  const int g0 = blockIdx.x * blockDim.x + threadIdx.x;
  for (int i = g0; i < 33554432; i += stride) seq_bf[i] = f2bf(seq[i]);
  for (int i = g0; i < 1048576; i += stride) {
    Wi_bf[i] = f2bf(Wi[i]);
    Wo_bf[i] = f2bf(Wo[i]);
    float wv = Wh[i];
    unsigned short hi = f2bf(wv);
    Wh_hi[i] = hi;
    Wh_lo[i] = f2bf(wv - bf2f(hi));
  }
  for (int i = g0; i < 65536; i += stride) hbuf[i] = 0;   // 2 groups x 2 bufs x 16x1024
  for (int i = g0; i < 256; i += stride) ctrs[i] = 0;
}

// ---------------------------------------------------------------- gemm ----
// C[M,N] = A[M,K] * B[N,K]^T + bias[N]. (unchanged from round 1 — passed)
template <typename AT>
__global__ __launch_bounds__(256) void gemm_bt(const AT* __restrict__ A,
                                               const unsigned short* __restrict__ Bm,
                                               const float* __restrict__ bias,
                                               float* __restrict__ C) {
  __shared__ unsigned short As[128 * 72];
  __shared__ unsigned short Bs[128 * 72];
  const int tid = threadIdx.x;
  const int nt = blockIdx.x & 7;
  const int mt = blockIdx.x >> 3;
  const int m0 = mt << 7, n0 = nt << 7;
  const int w = tid >> 6, l = tid & 63;
  const int wm = (w & 1) << 6, wn = (w >> 1) << 6;
  const int q = l >> 4, r = l & 15;
  const int srow = tid >> 1, shalf = tid & 1;
  f32x4 acc[4][4] = {};
  for (int k0 = 0; k0 < K_SZ; k0 += 64) {
    __syncthreads();
    {
      short8* dst = (short8*)(As + srow * 72 + shalf * 32);
      if constexpr (sizeof(AT) == 2) {
        const short8* src = (const short8*)(((const unsigned short*)A) + (size_t)(m0 + srow) * K_SZ + k0 + shalf * 32);
        #pragma unroll
        for (int i = 0; i < 4; ++i) dst[i] = src[i];
      } else {
        const float* srcf = ((const float*)A) + (size_t)(m0 + srow) * K_SZ + k0 + shalf * 32;
        #pragma unroll
        for (int i = 0; i < 4; ++i) {
          f32x4 fa = ((const f32x4*)srcf)[2 * i];
          f32x4 fb = ((const f32x4*)srcf)[2 * i + 1];
          short8 o;
          #pragma unroll
          for (int e = 0; e < 4; ++e) { o[e] = (short)f2bf(fa[e]); o[e + 4] = (short)f2bf(fb[e]); }
          dst[i] = o;
        }
      }
      const short8* srcb = (const short8*)(Bm + (size_t)(n0 + srow) * K_SZ + k0 + shalf * 32);
      short8* dstb = (short8*)(Bs + srow * 72 + shalf * 32);
      #pragma unroll
      for (int i = 0; i < 4; ++i) dstb[i] = srcb[i];
    }
    __syncthreads();
    #pragma unroll
    for (int c = 0; c < 2; ++c) {
      short8 af[4], bf[4];
      #pragma unroll
      for (int i = 0; i < 4; ++i)
        af[i] = *(const short8*)(As + (wm + i * 16 + r) * 72 + c * 32 + q * 8);
      #pragma unroll
      for (int j = 0; j < 4; ++j)
        bf[j] = *(const short8*)(Bs + (wn + j * 16 + r) * 72 + c * 32 + q * 8);
      #pragma unroll
      for (int i = 0; i < 4; ++i)
        #pragma unroll
        for (int j = 0; j < 4; ++j)
          acc[i][j] = __builtin_amdgcn_mfma_f32_16x16x32_bf16(af[i], bf[j], acc[i][j], 0, 0, 0);
    }
  }
  #pragma unroll
  for (int j = 0; j < 4; ++j) {
    const int n = n0 + wn + j * 16 + r;
    const float bv = bias[n];
    #pragma unroll
    for (int i = 0; i < 4; ++i) {
      #pragma unroll
      for (int e = 0; e < 4; ++e) {
        const int m = m0 + wm + i * 16 + q * 4 + e;
        C[(size_t)m * N_SZ + n] = acc[i][j][e] + bv;
      }
    }
  }
}

// ---------------------------------------------------------------- scan ----
// 2 groups x 16 batches x 16 blocks. Wave owns 16 H-rows, Wh hi/lo frags
// register-resident. h ping-pong through MALL: relaxed sc1 atomic dword
// stores (producer) / asm sc1 dwordx4 loads (consumer). Barrier: relaxed
// atomic counter, 16 arrivals, relaxed spin. NO fences in the loop.
__global__ __launch_bounds__(256, 1) void rnn_scan(const float* __restrict__ xp,
                                                   const unsigned short* __restrict__ Whh,
                                                   const unsigned short* __restrict__ Whl,
                                                   unsigned short* __restrict__ hbuf,
                                                   unsigned* __restrict__ ctrs,
                                                   float* __restrict__ hidden) {
  const int bid = blockIdx.x;      // 0..31
  const int g = bid >> 4;          // group 0..1 (16 batches each)
  const int slot = bid & 15;
  const int w = threadIdx.x >> 6, l = threadIdx.x & 63;
  const int q = l >> 4, r = l & 15;
  const int jbase = slot * 64 + w * 16;   // wave's 16 H-rows
  const int jl = jbase + r;
  const int b0 = g * 16;
  unsigned* ctr = ctrs + g * 64;
  unsigned short* hb = hbuf + g * 32768;  // [2][16][1024] ping-pong

  short8 whh[32], whl[32];                // resident Wh frags (hi+lo)
  {
    const size_t rowoff = (size_t)jl * 1024 + q * 8;
    #pragma unroll
    for (int c = 0; c < 32; ++c) {
      whh[c] = *(const short8*)(Whh + rowoff + c * 32);
      whl[c] = *(const short8*)(Whl + rowoff + c * 32);
    }
  }

  f32x4 xcur;
  #pragma unroll
  for (int e = 0; e < 4; ++e)
    xcur[e] = xp[(unsigned)(b0 + 4 * q + e) * 1048576u + jl];

  for (int t = 0; t < 1024; ++t) {
    const unsigned short* hc = hb + (t & 1) * 16384;
    unsigned short* hn = hb + ((t + 1) & 1) * 16384;
    // --- coherent h load: A-frag lane(r=batch, q) reads 8 bf16 at k=c*32+q*8
    const unsigned short* hrow = hc + r * 1024 + q * 8;
    short8 hf[32];
#define LDH(c) hf[c] = ldg_sc1<(c) * 64>(hrow);
    LDH(0) LDH(1) LDH(2) LDH(3) LDH(4) LDH(5) LDH(6) LDH(7)
    LDH(8) LDH(9) LDH(10) LDH(11) LDH(12) LDH(13) LDH(14) LDH(15)
    LDH(16) LDH(17) LDH(18) LDH(19) LDH(20) LDH(21) LDH(22) LDH(23)
    LDH(24) LDH(25) LDH(26) LDH(27) LDH(28) LDH(29) LDH(30) LDH(31)
#undef LDH
    f32x4 xnext = xcur;
    if (t + 1 < 1024) {
      #pragma unroll
      for (int e = 0; e < 4; ++e)
        xnext[e] = xp[(unsigned)(b0 + 4 * q + e) * 1048576u + (unsigned)(t + 1) * 1024u + jl];
    }
    asm volatile("s_waitcnt vmcnt(0)" ::: "memory");
    // --- MFMA: D[m=batch][n=H-row], 8 chains for ILP
    f32x4 ah0 = {}, ah1 = {}, ah2 = {}, ah3 = {};
    f32x4 al0 = {}, al1 = {}, al2 = {}, al3 = {};
    #pragma unroll
    for (int c = 0; c < 32; c += 4) {
      ah0 = __builtin_amdgcn_mfma_f32_16x16x32_bf16(hf[c + 0], whh[c + 0], ah0, 0, 0, 0);
      al0 = __builtin_amdgcn_mfma_f32_16x16x32_bf16(hf[c + 0], whl[c + 0], al0, 0, 0, 0);
      ah1 = __builtin_amdgcn_mfma_f32_16x16x32_bf16(hf[c + 1], whh[c + 1], ah1, 0, 0, 0);
      al1 = __builtin_amdgcn_mfma_f32_16x16x32_bf16(hf[c + 1], whl[c + 1], al1, 0, 0, 0);
      ah2 = __builtin_amdgcn_mfma_f32_16x16x32_bf16(hf[c + 2], whh[c + 2], ah2, 0, 0, 0);
      al2 = __builtin_amdgcn_mfma_f32_16x16x32_bf16(hf[c + 2], whl[c + 2], al2, 0, 0, 0);
      ah3 = __builtin_amdgcn_mfma_f32_16x16x32_bf16(hf[c + 3], whh[c + 3], ah3, 0, 0, 0);
      al3 = __builtin_amdgcn_mfma_f32_16x16x32_bf16(hf[c + 3], whl[c + 3], al3, 0, 0, 0);
    }
    f32x4 acc = ((ah0 + ah1) + (ah2 + ah3)) + ((al0 + al1) + (al2 + al3));
    // --- epilogue: C elem e -> batch b0+4q+e, column jl. Exact GELU.
    float hv[4], hu[4];
    #pragma unroll
    for (int e = 0; e < 4; ++e) {
      float z = acc[e] + xcur[e];
      hv[e] = 0.5f * z * (1.0f + erff(z * 0.70710678118654752f));
      hidden[(unsigned)(b0 + 4 * q + e) * 1048576u + (unsigned)t * 1024u + jl] = hv[e];
    }
    #pragma unroll
    for (int e = 0; e < 4; ++e) hu[e] = __shfl_xor(hv[e], 1);
    // lane-pair pack -> 2 coherent dword stores (write-through to MALL)
    {
      unsigned* hn32 = (unsigned*)hn;
      unsigned p0, p1; unsigned i0, i1;
      if ((l & 1) == 0) {
        p0 = (unsigned)f2bf(hv[0]) | ((unsigned)f2bf(hu[0]) << 16);
        p1 = (unsigned)f2bf(hv[1]) | ((unsigned)f2bf(hu[1]) << 16);
        i0 = ((unsigned)(4 * q + 0) * 1024u + jl) >> 1;
        i1 = ((unsigned)(4 * q + 1) * 1024u + jl) >> 1;
      } else {
        p0 = (unsigned)f2bf(hu[2]) | ((unsigned)f2bf(hv[2]) << 16);
        p1 = (unsigned)f2bf(hu[3]) | ((unsigned)f2bf(hv[3]) << 16);
        i0 = ((unsigned)(4 * q + 2) * 1024u + jl - 1) >> 1;
        i1 = ((unsigned)(4 * q + 3) * 1024u + jl - 1) >> 1;
      }
      __hip_atomic_store(hn32 + i0, p0, __ATOMIC_RELAXED, __HIP_MEMORY_SCOPE_AGENT);
      __hip_atomic_store(hn32 + i1, p1, __ATOMIC_RELAXED, __HIP_MEMORY_SCOPE_AGENT);
    }
    xcur = xnext;
    // --- barrier: drain stores (vmcnt), block barrier, relaxed arrive+spin
    __builtin_amdgcn_s_waitcnt(0);
    __syncthreads();
    if (threadIdx.x == 0) {
      __hip_atomic_fetch_add(ctr, 1u, __ATOMIC_RELAXED, __HIP_MEMORY_SCOPE_AGENT);
      const unsigned tgt = (unsigned)(t + 1) * 16u;
      long guard = 0;
      while (__hip_atomic_load(ctr, __ATOMIC_RELAXED, __HIP_MEMORY_SCOPE_AGENT) < tgt) {
        if (++guard > (1L << 30)) break;  // fail loud, never hang
      }
    }
    __syncthreads();
  }
}

// -------------------------------------------------------------- launch ----
extern "C" void kernel_launch(void* const* d_in, const int* in_sizes, int n_in,
                              void* d_out, int out_size, void* d_ws, size_t ws_size,
                              hipStream_t stream) {
  const float* seq = (const float*)d_in[0];
  const float* Wi  = (const float*)d_in[1];
  const float* bi  = (const float*)d_in[2];
  const float* Wh  = (const float*)d_in[3];
  const float* Wo  = (const float*)d_in[4];
  const float* bo  = (const float*)d_in[5];

  float* hidden = (float*)d_out;
  float* xproj  = (float*)d_out + (size_t)M_SZ * N_SZ;
  unsigned short* seq_bf = (unsigned short*)d_out;   // aliases hidden; dead until scan

  char* ws = (char*)d_ws;
  unsigned short* Wi_bf = (unsigned short*)(ws);
  unsigned short* Wo_bf = (unsigned short*)(ws + (2u << 20));
  unsigned short* Wh_hi = (unsigned short*)(ws + (4u << 20));
  unsigned short* Wh_lo = (unsigned short*)(ws + (6u << 20));
  unsigned short* hbuf  = (unsigned short*)(ws + (8u << 20));          // 128 KB
  unsigned* ctrs        = (unsigned*)(ws + (8u << 20) + (256u << 10)); // 2 x 256B

  prep<<<4096, 256, 0, stream>>>(seq, Wi, Wh, Wo, seq_bf, Wi_bf, Wh_hi, Wh_lo, Wo_bf, hbuf, ctrs);
  gemm_bt<unsigned short><<<2048, 256, 0, stream>>>(seq_bf, Wi_bf, bi, xproj);
  rnn_scan<<<32, 256, 0, stream>>>(xproj, Wh_hi, Wh_lo, hbuf, ctrs, hidden);
  gemm_bt<float><<<2048, 256, 0, stream>>>(hidden, Wo_bf, bo, xproj);
}

// Round 4
// 7273.962 us; speedup vs baseline: 1.0106x; 1.0106x over previous
//
#include <hip/hip_runtime.h>
#include <hip/hip_bf16.h>
#include <math.h>

typedef __attribute__((ext_vector_type(8))) short short8;
typedef __attribute__((ext_vector_type(4))) float f32x4;

#define M_SZ 32768   // B*T
#define K_SZ 1024
#define N_SZ 1024

__device__ __forceinline__ unsigned short f2bf(float f) {
  union { float f; unsigned u; } v; v.f = f;
  unsigned r = v.u + 0x7fffu + ((v.u >> 16) & 1u);
  return (unsigned short)(r >> 16);
}
__device__ __forceinline__ float bf2f(unsigned short b) {
  union { unsigned u; float f; } v; v.u = ((unsigned)b) << 16;
  return v.f;
}

// Coherent 16B load: bypasses (possibly stale) L1/L2, reads the MALL — the
// cross-XCD coherence point — with NO cache invalidation. (Round-1 proven.)
template <int OFF>
__device__ __forceinline__ short8 ldg_sc1(const unsigned short* p) {
  short8 r;
  asm volatile("global_load_dwordx4 %0, %1, off offset:%c2 sc1"
               : "=v"(r) : "v"(p), "i"(OFF) : "memory");
  return r;
}

// Coherent dword load + drain, for the flag poll.
__device__ __forceinline__ unsigned ld_u32_sc1(const unsigned* p) {
  unsigned r;
  asm volatile("global_load_dword %0, %1, off sc1\n\ts_waitcnt vmcnt(0)"
               : "=v"(r) : "v"(p) : "memory");
  return r;
}

// ---------------------------------------------------------------- prep ----
__global__ void prep(const float* __restrict__ seq, const float* __restrict__ Wi,
                     const float* __restrict__ Wh, const float* __restrict__ Wo,
                     unsigned short* __restrict__ seq_bf, unsigned short* __restrict__ Wi_bf,
                     unsigned short* __restrict__ Wh_hi, unsigned short* __restrict__ Wh_lo,
                     unsigned short* __restrict__ Wo_bf, unsigned short* __restrict__ hbuf,
                     unsigned* __restrict__ flags) {
  const int stride = gridDim.x * blockDim.x;
  const int g0 = blockIdx.x * blockDim.x + threadIdx.x;
  for (int i = g0; i < 33554432; i += stride) seq_bf[i] = f2bf(seq[i]);
  for (int i = g0; i < 1048576; i += stride) {
    Wi_bf[i] = f2bf(Wi[i]);
    Wo_bf[i] = f2bf(Wo[i]);
    float wv = Wh[i];
    unsigned short hi = f2bf(wv);
    Wh_hi[i] = hi;
    Wh_lo[i] = f2bf(wv - bf2f(hi));
  }
  for (int i = g0; i < 65536; i += stride) hbuf[i] = 0;   // 2 groups x 2 bufs x 16x1024
  for (int i = g0; i < 2048; i += stride) flags[i] = 0;   // 2 groups x 16 flag lines
}

// ---------------------------------------------------------------- gemm ----
// C[M,N] = A[M,K] * B[N,K]^T + bias[N]. (unchanged — passed)
template <typename AT>
__global__ __launch_bounds__(256) void gemm_bt(const AT* __restrict__ A,
                                               const unsigned short* __restrict__ Bm,
                                               const float* __restrict__ bias,
                                               float* __restrict__ C) {
  __shared__ unsigned short As[128 * 72];
  __shared__ unsigned short Bs[128 * 72];
  const int tid = threadIdx.x;
  const int nt = blockIdx.x & 7;
  const int mt = blockIdx.x >> 3;
  const int m0 = mt << 7, n0 = nt << 7;
  const int w = tid >> 6, l = tid & 63;
  const int wm = (w & 1) << 6, wn = (w >> 1) << 6;
  const int q = l >> 4, r = l & 15;
  const int srow = tid >> 1, shalf = tid & 1;
  f32x4 acc[4][4] = {};
  for (int k0 = 0; k0 < K_SZ; k0 += 64) {
    __syncthreads();
    {
      short8* dst = (short8*)(As + srow * 72 + shalf * 32);
      if constexpr (sizeof(AT) == 2) {
        const short8* src = (const short8*)(((const unsigned short*)A) + (size_t)(m0 + srow) * K_SZ + k0 + shalf * 32);
        #pragma unroll
        for (int i = 0; i < 4; ++i) dst[i] = src[i];
      } else {
        const float* srcf = ((const float*)A) + (size_t)(m0 + srow) * K_SZ + k0 + shalf * 32;
        #pragma unroll
        for (int i = 0; i < 4; ++i) {
          f32x4 fa = ((const f32x4*)srcf)[2 * i];
          f32x4 fb = ((const f32x4*)srcf)[2 * i + 1];
          short8 o;
          #pragma unroll
          for (int e = 0; e < 4; ++e) { o[e] = (short)f2bf(fa[e]); o[e + 4] = (short)f2bf(fb[e]); }
          dst[i] = o;
        }
      }
      const short8* srcb = (const short8*)(Bm + (size_t)(n0 + srow) * K_SZ + k0 + shalf * 32);
      short8* dstb = (short8*)(Bs + srow * 72 + shalf * 32);
      #pragma unroll
      for (int i = 0; i < 4; ++i) dstb[i] = srcb[i];
    }
    __syncthreads();
    #pragma unroll
    for (int c = 0; c < 2; ++c) {
      short8 af[4], bf[4];
      #pragma unroll
      for (int i = 0; i < 4; ++i)
        af[i] = *(const short8*)(As + (wm + i * 16 + r) * 72 + c * 32 + q * 8);
      #pragma unroll
      for (int j = 0; j < 4; ++j)
        bf[j] = *(const short8*)(Bs + (wn + j * 16 + r) * 72 + c * 32 + q * 8);
      #pragma unroll
      for (int i = 0; i < 4; ++i)
        #pragma unroll
        for (int j = 0; j < 4; ++j)
          acc[i][j] = __builtin_amdgcn_mfma_f32_16x16x32_bf16(af[i], bf[j], acc[i][j], 0, 0, 0);
    }
  }
  #pragma unroll
  for (int j = 0; j < 4; ++j) {
    const int n = n0 + wn + j * 16 + r;
    const float bv = bias[n];
    #pragma unroll
    for (int i = 0; i < 4; ++i) {
      #pragma unroll
      for (int e = 0; e < 4; ++e) {
        const int m = m0 + wm + i * 16 + q * 4 + e;
        C[(size_t)m * N_SZ + n] = acc[i][j][e] + bv;
      }
    }
  }
}

// ---------------------------------------------------------------- scan ----
// Round-1 proven MALL protocol (grid=32, fixed roles, sc1 loads, agent-scope
// relaxed atomic stores). Round-4 change: the barrier. The old single-counter
// barrier serialized 16 RMW arrivals + 16 RMW spinners on ONE cacheline at
// the MALL (the hidden ~10k cycles/step). Now: distributed flags, one 128B
// line per block. Arrive = one sc1 dword store (after h-drain); detect = one
// wave-wide sc1 load over 16 lines + __ballot. No RMW anywhere in the loop.
// Also: partial drain (vmcnt(4)) keeps the fp32 hidden HBM stores off the
// critical path (only the 2 sc1 h-stores gate the flag).
__global__ __launch_bounds__(256, 1) void rnn_scan(const float* __restrict__ xp,
                                                   const unsigned short* __restrict__ Whh,
                                                   const unsigned short* __restrict__ Whl,
                                                   unsigned short* __restrict__ hbuf,
                                                   unsigned* __restrict__ flags,
                                                   float* __restrict__ hidden) {
  const int bid = blockIdx.x;      // 0..31
  const int g = bid >> 4;          // group 0..1 (16 batches each)
  const int slot = bid & 15;
  const int w = threadIdx.x >> 6, l = threadIdx.x & 63;
  const int q = l >> 4, r = l & 15;
  const int jbase = slot * 64 + w * 16;   // wave's 16 H-rows
  const int jl = jbase + r;
  const int b0 = g * 16;
  unsigned* gflags = flags + g * 512;     // 16 flags, 32-dword (128B) stride
  unsigned short* hb = hbuf + g * 32768;  // [2][16][1024] ping-pong

  short8 whh[32], whl[32];                // resident Wh frags (hi+lo)
  {
    const size_t rowoff = (size_t)jl * 1024 + q * 8;
    #pragma unroll
    for (int c = 0; c < 32; ++c) {
      whh[c] = *(const short8*)(Whh + rowoff + c * 32);
      whl[c] = *(const short8*)(Whl + rowoff + c * 32);
    }
  }

  f32x4 xcur;
  #pragma unroll
  for (int e = 0; e < 4; ++e)
    xcur[e] = xp[(unsigned)(b0 + 4 * q + e) * 1048576u + jl];

  const unsigned* pollp = gflags + (l & 15) * 32;  // lane l polls flag (l&15)
  unsigned dead = 0;                               // latched guard (no hang)

  for (int t = 0; t < 1024; ++t) {
    const unsigned short* hc = hb + (t & 1) * 16384;
    unsigned short* hn = hb + ((t + 1) & 1) * 16384;
    // --- coherent h load: A-frag lane(r=batch, q) reads 8 bf16 at k=c*32+q*8
    const unsigned short* hrow = hc + r * 1024 + q * 8;
    short8 hf[32];
#define LDH(c) hf[c] = ldg_sc1<(c) * 64>(hrow);
    LDH(0) LDH(1) LDH(2) LDH(3) LDH(4) LDH(5) LDH(6) LDH(7)
    LDH(8) LDH(9) LDH(10) LDH(11) LDH(12) LDH(13) LDH(14) LDH(15)
    LDH(16) LDH(17) LDH(18) LDH(19) LDH(20) LDH(21) LDH(22) LDH(23)
    LDH(24) LDH(25) LDH(26) LDH(27) LDH(28) LDH(29) LDH(30) LDH(31)
#undef LDH
    f32x4 xnext = xcur;
    if (t + 1 < 1024) {
      #pragma unroll
      for (int e = 0; e < 4; ++e)
        xnext[e] = xp[(unsigned)(b0 + 4 * q + e) * 1048576u + (unsigned)(t + 1) * 1024u + jl];
    }
    asm volatile("s_waitcnt vmcnt(0)" ::: "memory");
    // --- MFMA: D[m=batch][n=H-row], 8 chains for ILP
    f32x4 ah0 = {}, ah1 = {}, ah2 = {}, ah3 = {};
    f32x4 al0 = {}, al1 = {}, al2 = {}, al3 = {};
    #pragma unroll
    for (int c = 0; c < 32; c += 4) {
      ah0 = __builtin_amdgcn_mfma_f32_16x16x32_bf16(hf[c + 0], whh[c + 0], ah0, 0, 0, 0);
      al0 = __builtin_amdgcn_mfma_f32_16x16x32_bf16(hf[c + 0], whl[c + 0], al0, 0, 0, 0);
      ah1 = __builtin_amdgcn_mfma_f32_16x16x32_bf16(hf[c + 1], whh[c + 1], ah1, 0, 0, 0);
      al1 = __builtin_amdgcn_mfma_f32_16x16x32_bf16(hf[c + 1], whl[c + 1], al1, 0, 0, 0);
      ah2 = __builtin_amdgcn_mfma_f32_16x16x32_bf16(hf[c + 2], whh[c + 2], ah2, 0, 0, 0);
      al2 = __builtin_amdgcn_mfma_f32_16x16x32_bf16(hf[c + 2], whl[c + 2], al2, 0, 0, 0);
      ah3 = __builtin_amdgcn_mfma_f32_16x16x32_bf16(hf[c + 3], whh[c + 3], ah3, 0, 0, 0);
      al3 = __builtin_amdgcn_mfma_f32_16x16x32_bf16(hf[c + 3], whl[c + 3], al3, 0, 0, 0);
    }
    f32x4 acc = ((ah0 + ah1) + (ah2 + ah3)) + ((al0 + al1) + (al2 + al3));
    // --- epilogue: C elem e -> batch b0+4q+e, column jl. Exact GELU.
    float hv[4], hu[4];
    #pragma unroll
    for (int e = 0; e < 4; ++e) {
      float z = acc[e] + xcur[e];
      hv[e] = 0.5f * z * (1.0f + erff(z * 0.70710678118654752f));
    }
    #pragma unroll
    for (int e = 0; e < 4; ++e) hu[e] = __shfl_xor(hv[e], 1);
    // --- h stores FIRST (oldest in vmcnt order): 2 sc1 dword stores
    {
      unsigned* hn32 = (unsigned*)hn;
      unsigned p0, p1; unsigned i0, i1;
      if ((l & 1) == 0) {
        p0 = (unsigned)f2bf(hv[0]) | ((unsigned)f2bf(hu[0]) << 16);
        p1 = (unsigned)f2bf(hv[1]) | ((unsigned)f2bf(hu[1]) << 16);
        i0 = ((unsigned)(4 * q + 0) * 1024u + jl) >> 1;
        i1 = ((unsigned)(4 * q + 1) * 1024u + jl) >> 1;
      } else {
        p0 = (unsigned)f2bf(hu[2]) | ((unsigned)f2bf(hv[2]) << 16);
        p1 = (unsigned)f2bf(hu[3]) | ((unsigned)f2bf(hv[3]) << 16);
        i0 = ((unsigned)(4 * q + 2) * 1024u + jl - 1) >> 1;
        i1 = ((unsigned)(4 * q + 3) * 1024u + jl - 1) >> 1;
      }
      __hip_atomic_store(hn32 + i0, p0, __ATOMIC_RELAXED, __HIP_MEMORY_SCOPE_AGENT);
      __hip_atomic_store(hn32 + i1, p1, __ATOMIC_RELAXED, __HIP_MEMORY_SCOPE_AGENT);
    }
    asm volatile("" ::: "memory");   // pin order: h stores before hidden stores
    // --- hidden stores (HBM, NOT drained on the critical path)
    #pragma unroll
    for (int e = 0; e < 4; ++e)
      hidden[(unsigned)(b0 + 4 * q + e) * 1048576u + (unsigned)t * 1024u + jl] = hv[e];
    xcur = xnext;
    // --- partial drain: retire the 2 oldest (h) stores; hidden may linger
    asm volatile("s_waitcnt vmcnt(4)" ::: "memory");
    __syncthreads();                 // all waves' h stores are at the MALL
    if (threadIdx.x == 0)
      __hip_atomic_store(gflags + slot * 32, (unsigned)(t + 1),
                         __ATOMIC_RELAXED, __HIP_MEMORY_SCOPE_AGENT);
    // --- detect: every wave polls all 16 flags with one wave-wide sc1 load
    if (!dead) {
      const unsigned tgt = (unsigned)(t + 1);
      int guard = 0;
      for (;;) {
        unsigned v = ld_u32_sc1(pollp);
        if (__ballot(v >= tgt) == ~0ull) break;
        if (++guard > (1 << 22)) { dead = 1; break; }  // fail loud, never hang
      }
    }
  }
}

// -------------------------------------------------------------- launch ----
extern "C" void kernel_launch(void* const* d_in, const int* in_sizes, int n_in,
                              void* d_out, int out_size, void* d_ws, size_t ws_size,
                              hipStream_t stream) {
  const float* seq = (const float*)d_in[0];
  const float* Wi  = (const float*)d_in[1];
  const float* bi  = (const float*)d_in[2];
  const float* Wh  = (const float*)d_in[3];
  const float* Wo  = (const float*)d_in[4];
  const float* bo  = (const float*)d_in[5];

  float* hidden = (float*)d_out;
  float* xproj  = (float*)d_out + (size_t)M_SZ * N_SZ;
  unsigned short* seq_bf = (unsigned short*)d_out;   // aliases hidden; dead until scan

  char* ws = (char*)d_ws;
  unsigned short* Wi_bf = (unsigned short*)(ws);
  unsigned short* Wo_bf = (unsigned short*)(ws + (2u << 20));
  unsigned short* Wh_hi = (unsigned short*)(ws + (4u << 20));
  unsigned short* Wh_lo = (unsigned short*)(ws + (6u << 20));
  unsigned short* hbuf  = (unsigned short*)(ws + (8u << 20));          // 128 KB
  unsigned* flags       = (unsigned*)(ws + (8u << 20) + (256u << 10)); // 2 x 16 x 128B

  prep<<<4096, 256, 0, stream>>>(seq, Wi, Wh, Wo, seq_bf, Wi_bf, Wh_hi, Wh_lo, Wo_bf, hbuf, flags);
  gemm_bt<unsigned short><<<2048, 256, 0, stream>>>(seq_bf, Wi_bf, bi, xproj);
  rnn_scan<<<32, 256, 0, stream>>>(xproj, Wh_hi, Wh_lo, hbuf, flags, hidden);
  gemm_bt<float><<<2048, 256, 0, stream>>>(hidden, Wo_bf, bo, xproj);
}

// Round 6
// 4364.345 us; speedup vs baseline: 1.6844x; 1.6667x over previous
//
#include <hip/hip_runtime.h>
#include <hip/hip_bf16.h>
#include <math.h>

typedef __attribute__((ext_vector_type(8))) short short8;
typedef __attribute__((ext_vector_type(4))) float f32x4;

#define M_SZ 32768   // B*T
#define K_SZ 1024
#define N_SZ 1024

__device__ __forceinline__ unsigned short f2bf(float f) {
  union { float f; unsigned u; } v; v.f = f;
  unsigned r = v.u + 0x7fffu + ((v.u >> 16) & 1u);
  return (unsigned short)(r >> 16);
}
__device__ __forceinline__ float bf2f(unsigned short b) {
  union { unsigned u; float f; } v; v.u = ((unsigned)b) << 16;
  return v.f;
}

// Coherent 16B load from the MALL (cross-XCD coherence point). Round-1 proven.
// NOTE: inline-asm loads are INVISIBLE to the compiler's vmcnt bookkeeping —
// every consumer path must have an explicit s_waitcnt vmcnt(0) (round-5 NaN).
__device__ __forceinline__ short8 ldg_sc1p(const unsigned short* p) {
  short8 r;
  asm volatile("global_load_dwordx4 %0, %1, off sc1"
               : "=v"(r) : "v"(p) : "memory");
  return r;
}

// Coherent dword load + drain, for the flag poll.
__device__ __forceinline__ unsigned ld_u32_sc1(const unsigned* p) {
  unsigned r;
  asm volatile("global_load_dword %0, %1, off sc1\n\ts_waitcnt vmcnt(0)"
               : "=v"(r) : "v"(p) : "memory");
  return r;
}

// ---------------------------------------------------------------- prep ----
__global__ void prep(const float* __restrict__ seq, const float* __restrict__ Wi,
                     const float* __restrict__ Wh, const float* __restrict__ Wo,
                     unsigned short* __restrict__ seq_bf, unsigned short* __restrict__ Wi_bf,
                     unsigned short* __restrict__ Wh_hi, unsigned short* __restrict__ Wh_lo,
                     unsigned short* __restrict__ Wo_bf, unsigned short* __restrict__ hbuf,
                     unsigned* __restrict__ flags) {
  const int stride = gridDim.x * blockDim.x;
  const int g0 = blockIdx.x * blockDim.x + threadIdx.x;
  for (int i = g0; i < 33554432; i += stride) seq_bf[i] = f2bf(seq[i]);
  for (int i = g0; i < 1048576; i += stride) {
    Wi_bf[i] = f2bf(Wi[i]);
    Wo_bf[i] = f2bf(Wo[i]);
    float wv = Wh[i];
    unsigned short hi = f2bf(wv);
    Wh_hi[i] = hi;
    Wh_lo[i] = f2bf(wv - bf2f(hi));
  }
  for (int i = g0; i < 65536; i += stride) hbuf[i] = 0;   // 2 groups x 2 bufs x 16x1024
  for (int i = g0; i < 2048; i += stride) flags[i] = 0;   // 2 groups x 16 flag lines
}

// ---------------------------------------------------------------- gemm ----
// C[M,N] = A[M,K] * B[N,K]^T + bias[N]. (unchanged — passed)
template <typename AT>
__global__ __launch_bounds__(256) void gemm_bt(const AT* __restrict__ A,
                                               const unsigned short* __restrict__ Bm,
                                               const float* __restrict__ bias,
                                               float* __restrict__ C) {
  __shared__ unsigned short As[128 * 72];
  __shared__ unsigned short Bs[128 * 72];
  const int tid = threadIdx.x;
  const int nt = blockIdx.x & 7;
  const int mt = blockIdx.x >> 3;
  const int m0 = mt << 7, n0 = nt << 7;
  const int w = tid >> 6, l = tid & 63;
  const int wm = (w & 1) << 6, wn = (w >> 1) << 6;
  const int q = l >> 4, r = l & 15;
  const int srow = tid >> 1, shalf = tid & 1;
  f32x4 acc[4][4] = {};
  for (int k0 = 0; k0 < K_SZ; k0 += 64) {
    __syncthreads();
    {
      short8* dst = (short8*)(As + srow * 72 + shalf * 32);
      if constexpr (sizeof(AT) == 2) {
        const short8* src = (const short8*)(((const unsigned short*)A) + (size_t)(m0 + srow) * K_SZ + k0 + shalf * 32);
        #pragma unroll
        for (int i = 0; i < 4; ++i) dst[i] = src[i];
      } else {
        const float* srcf = ((const float*)A) + (size_t)(m0 + srow) * K_SZ + k0 + shalf * 32;
        #pragma unroll
        for (int i = 0; i < 4; ++i) {
          f32x4 fa = ((const f32x4*)srcf)[2 * i];
          f32x4 fb = ((const f32x4*)srcf)[2 * i + 1];
          short8 o;
          #pragma unroll
          for (int e = 0; e < 4; ++e) { o[e] = (short)f2bf(fa[e]); o[e + 4] = (short)f2bf(fb[e]); }
          dst[i] = o;
        }
      }
      const short8* srcb = (const short8*)(Bm + (size_t)(n0 + srow) * K_SZ + k0 + shalf * 32);
      short8* dstb = (short8*)(Bs + srow * 72 + shalf * 32);
      #pragma unroll
      for (int i = 0; i < 4; ++i) dstb[i] = srcb[i];
    }
    __syncthreads();
    #pragma unroll
    for (int c = 0; c < 2; ++c) {
      short8 af[4], bf[4];
      #pragma unroll
      for (int i = 0; i < 4; ++i)
        af[i] = *(const short8*)(As + (wm + i * 16 + r) * 72 + c * 32 + q * 8);
      #pragma unroll
      for (int j = 0; j < 4; ++j)
        bf[j] = *(const short8*)(Bs + (wn + j * 16 + r) * 72 + c * 32 + q * 8);
      #pragma unroll
      for (int i = 0; i < 4; ++i)
        #pragma unroll
        for (int j = 0; j < 4; ++j)
          acc[i][j] = __builtin_amdgcn_mfma_f32_16x16x32_bf16(af[i], bf[j], acc[i][j], 0, 0, 0);
    }
  }
  #pragma unroll
  for (int j = 0; j < 4; ++j) {
    const int n = n0 + wn + j * 16 + r;
    const float bv = bias[n];
    #pragma unroll
    for (int i = 0; i < 4; ++i) {
      #pragma unroll
      for (int e = 0; e < 4; ++e) {
        const int m = m0 + wm + i * 16 + q * 4 + e;
        C[(size_t)m * N_SZ + n] = acc[i][j][e] + bv;
      }
    }
  }
}

// ---------------------------------------------------------------- scan ----
// Sync protocol: identical to the PASSING round-4 kernel (grid=32, fixed
// roles, sc1/MALL, distributed flags, partial drain).
// Data path (round 5/6): block cooperatively loads the 32KB h-tile COALESCED
// (256 threads x 8 consecutive dwordx4; each 128B line fetched once = 256
// MALL line-requests vs 8192 scattered in round 4), stages in LDS (row
// stride 1040 bf16 => fragment b128 reads sit at the 8cy LDS floor, even
// quad distribution), then waves read fragments with ds_read_b128.
// Round-6 fix vs round-5 NaN: restore the explicit s_waitcnt vmcnt(0)
// between the inline-asm tile loads and the LDS stores (asm loads are not
// tracked by the compiler's automatic waitcnt insertion).
__global__ __launch_bounds__(256, 1) void rnn_scan(const float* __restrict__ xp,
                                                   const unsigned short* __restrict__ Whh,
                                                   const unsigned short* __restrict__ Whl,
                                                   unsigned short* __restrict__ hbuf,
                                                   unsigned* __restrict__ flags,
                                                   float* __restrict__ hidden) {
  __shared__ __align__(16) unsigned short hs[16 * 1040];  // 33.3 KB staging tile

  const int bid = blockIdx.x;      // 0..31
  const int g = bid >> 4;          // group 0..1 (16 batches each)
  const int slot = bid & 15;
  const int tid = threadIdx.x;
  const int w = tid >> 6, l = tid & 63;
  const int q = l >> 4, r = l & 15;
  const int jbase = slot * 64 + w * 16;   // wave's 16 H-rows
  const int jl = jbase + r;
  const int b0 = g * 16;
  unsigned* gflags = flags + g * 512;     // 16 flags, 32-dword (128B) stride
  unsigned short* hb = hbuf + g * 32768;  // [2][16][1024] ping-pong

  short8 whh[32], whl[32];                // resident Wh frags (hi+lo)
  {
    const size_t rowoff = (size_t)jl * 1024 + q * 8;
    #pragma unroll
    for (int c = 0; c < 32; ++c) {
      whh[c] = *(const short8*)(Whh + rowoff + c * 32);
      whl[c] = *(const short8*)(Whl + rowoff + c * 32);
    }
  }

  // LDS destinations for this thread's 8 cooperative granules (G = k*256+tid)
  // src elem = 8G; row = G>>7, col = (G&127)*8, padded row stride 1040.
  unsigned short* dst_lds[8];
  #pragma unroll
  for (int k = 0; k < 8; ++k) {
    const int G = k * 256 + tid;
    dst_lds[k] = hs + (G >> 7) * 1040 + (G & 127) * 8;
  }
  const unsigned short* frag_lds = hs + r * 1040 + q * 8;

  f32x4 xcur;
  #pragma unroll
  for (int e = 0; e < 4; ++e)
    xcur[e] = xp[(unsigned)(b0 + 4 * q + e) * 1048576u + jl];

  const unsigned* pollp = gflags + (l & 15) * 32;  // lane l polls flag (l&15)
  unsigned dead = 0;                               // latched guard (no hang)

  for (int t = 0; t < 1024; ++t) {
    const unsigned short* hc = hb + (t & 1) * 16384;
    unsigned short* hn = hb + ((t + 1) & 1) * 16384;
    // --- cooperative COALESCED sc1 load of the whole 16x1024 h-tile
    const unsigned short* src = hc + tid * 8;
    short8 tile[8];
    #pragma unroll
    for (int k = 0; k < 8; ++k) tile[k] = ldg_sc1p(src + k * 2048);
    // --- x prefetch for t+1 (cached path, overlaps)
    f32x4 xnext = xcur;
    if (t + 1 < 1024) {
      #pragma unroll
      for (int e = 0; e < 4; ++e)
        xnext[e] = xp[(unsigned)(b0 + 4 * q + e) * 1048576u + (unsigned)(t + 1) * 1024u + jl];
    }
    // --- ROUND-6 FIX: asm loads are untracked; drain them before LDS stage
    asm volatile("s_waitcnt vmcnt(0)" ::: "memory");
    // --- stage to LDS
    #pragma unroll
    for (int k = 0; k < 8; ++k) *(short8*)dst_lds[k] = tile[k];
    __syncthreads();                 // tile visible to all waves
    // --- fragments from LDS: lane(r,q) reads 8 bf16 at k=c*32+q*8
    short8 hf[32];
    #pragma unroll
    for (int c = 0; c < 32; ++c)
      hf[c] = *(const short8*)(frag_lds + c * 32);
    // --- MFMA: D[m=batch][n=H-row], 8 chains for ILP
    f32x4 ah0 = {}, ah1 = {}, ah2 = {}, ah3 = {};
    f32x4 al0 = {}, al1 = {}, al2 = {}, al3 = {};
    #pragma unroll
    for (int c = 0; c < 32; c += 4) {
      ah0 = __builtin_amdgcn_mfma_f32_16x16x32_bf16(hf[c + 0], whh[c + 0], ah0, 0, 0, 0);
      al0 = __builtin_amdgcn_mfma_f32_16x16x32_bf16(hf[c + 0], whl[c + 0], al0, 0, 0, 0);
      ah1 = __builtin_amdgcn_mfma_f32_16x16x32_bf16(hf[c + 1], whh[c + 1], ah1, 0, 0, 0);
      al1 = __builtin_amdgcn_mfma_f32_16x16x32_bf16(hf[c + 1], whl[c + 1], al1, 0, 0, 0);
      ah2 = __builtin_amdgcn_mfma_f32_16x16x32_bf16(hf[c + 2], whh[c + 2], ah2, 0, 0, 0);
      al2 = __builtin_amdgcn_mfma_f32_16x16x32_bf16(hf[c + 2], whl[c + 2], al2, 0, 0, 0);
      ah3 = __builtin_amdgcn_mfma_f32_16x16x32_bf16(hf[c + 3], whh[c + 3], ah3, 0, 0, 0);
      al3 = __builtin_amdgcn_mfma_f32_16x16x32_bf16(hf[c + 3], whl[c + 3], al3, 0, 0, 0);
    }
    f32x4 acc = ((ah0 + ah1) + (ah2 + ah3)) + ((al0 + al1) + (al2 + al3));
    // --- epilogue: C elem e -> batch b0+4q+e, column jl. Exact GELU.
    float hv[4], hu[4];
    #pragma unroll
    for (int e = 0; e < 4; ++e) {
      float z = acc[e] + xcur[e];
      hv[e] = 0.5f * z * (1.0f + erff(z * 0.70710678118654752f));
    }
    #pragma unroll
    for (int e = 0; e < 4; ++e) hu[e] = __shfl_xor(hv[e], 1);
    // --- h stores FIRST (oldest in vmcnt order): 2 sc1 dword stores
    {
      unsigned* hn32 = (unsigned*)hn;
      unsigned p0, p1; unsigned i0, i1;
      if ((l & 1) == 0) {
        p0 = (unsigned)f2bf(hv[0]) | ((unsigned)f2bf(hu[0]) << 16);
        p1 = (unsigned)f2bf(hv[1]) | ((unsigned)f2bf(hu[1]) << 16);
        i0 = ((unsigned)(4 * q + 0) * 1024u + jl) >> 1;
        i1 = ((unsigned)(4 * q + 1) * 1024u + jl) >> 1;
      } else {
        p0 = (unsigned)f2bf(hu[2]) | ((unsigned)f2bf(hv[2]) << 16);
        p1 = (unsigned)f2bf(hu[3]) | ((unsigned)f2bf(hv[3]) << 16);
        i0 = ((unsigned)(4 * q + 2) * 1024u + jl - 1) >> 1;
        i1 = ((unsigned)(4 * q + 3) * 1024u + jl - 1) >> 1;
      }
      __hip_atomic_store(hn32 + i0, p0, __ATOMIC_RELAXED, __HIP_MEMORY_SCOPE_AGENT);
      __hip_atomic_store(hn32 + i1, p1, __ATOMIC_RELAXED, __HIP_MEMORY_SCOPE_AGENT);
    }
    asm volatile("" ::: "memory");   // pin order: h stores before hidden stores
    // --- hidden stores (HBM, NOT drained on the critical path)
    #pragma unroll
    for (int e = 0; e < 4; ++e)
      hidden[(unsigned)(b0 + 4 * q + e) * 1048576u + (unsigned)t * 1024u + jl] = hv[e];
    xcur = xnext;
    // --- partial drain: retire the 2 oldest (h) stores; hidden may linger
    asm volatile("s_waitcnt vmcnt(4)" ::: "memory");
    __syncthreads();                 // all waves' h stores are at the MALL
    if (threadIdx.x == 0)
      __hip_atomic_store(gflags + slot * 32, (unsigned)(t + 1),
                         __ATOMIC_RELAXED, __HIP_MEMORY_SCOPE_AGENT);
    // --- detect: every wave polls all 16 flags with one wave-wide sc1 load
    if (!dead) {
      const unsigned tgt = (unsigned)(t + 1);
      int guard = 0;
      for (;;) {
        unsigned v = ld_u32_sc1(pollp);
        if (__ballot(v >= tgt) == ~0ull) break;
        if (++guard > (1 << 22)) { dead = 1; break; }  // fail loud, never hang
      }
    }
  }
}

// -------------------------------------------------------------- launch ----
extern "C" void kernel_launch(void* const* d_in, const int* in_sizes, int n_in,
                              void* d_out, int out_size, void* d_ws, size_t ws_size,
                              hipStream_t stream) {
  const float* seq = (const float*)d_in[0];
  const float* Wi  = (const float*)d_in[1];
  const float* bi  = (const float*)d_in[2];
  const float* Wh  = (const float*)d_in[3];
  const float* Wo  = (const float*)d_in[4];
  const float* bo  = (const float*)d_in[5];

  float* hidden = (float*)d_out;
  float* xproj  = (float*)d_out + (size_t)M_SZ * N_SZ;
  unsigned short* seq_bf = (unsigned short*)d_out;   // aliases hidden; dead until scan

  char* ws = (char*)d_ws;
  unsigned short* Wi_bf = (unsigned short*)(ws);
  unsigned short* Wo_bf = (unsigned short*)(ws + (2u << 20));
  unsigned short* Wh_hi = (unsigned short*)(ws + (4u << 20));
  unsigned short* Wh_lo = (unsigned short*)(ws + (6u << 20));
  unsigned short* hbuf  = (unsigned short*)(ws + (8u << 20));          // 128 KB
  unsigned* flags       = (unsigned*)(ws + (8u << 20) + (256u << 10)); // 2 x 16 x 128B

  prep<<<4096, 256, 0, stream>>>(seq, Wi, Wh, Wo, seq_bf, Wi_bf, Wh_hi, Wh_lo, Wo_bf, hbuf, flags);
  gemm_bt<unsigned short><<<2048, 256, 0, stream>>>(seq_bf, Wi_bf, bi, xproj);
  rnn_scan<<<32, 256, 0, stream>>>(xproj, Wh_hi, Wh_lo, hbuf, flags, hidden);
  gemm_bt<float><<<2048, 256, 0, stream>>>(hidden, Wo_bf, bo, xproj);
}